// Round 4
// baseline (229.817 us; speedup 1.0000x reference)
//
#include <hip/hip_runtime.h>
#include <hip/hip_bf16.h>
#include <math.h>

// (B, D, H, W, K) = (32, 256, 64, 64, 64); N = H*W = 4096
#define BB 32
#define DD 256
#define NN 4096
#define KK 64
#define EPSV 1e-8f
#define XSTR 264   // xnd row stride (shorts): 528 B = 16B-aligned, bank-rotating

typedef __attribute__((ext_vector_type(8))) short short8;   // 8 bf16
typedef __attribute__((ext_vector_type(4))) float f32x4;

__device__ __forceinline__ unsigned int bf16pair(float a, float b) {
    __hip_bfloat162 h = __float22bfloat162_rn(make_float2(a, b));  // v_cvt_pk_bf16_f32 (RNE)
    return *(unsigned int*)&h;
}
__device__ __forceinline__ unsigned short bf16one(float a) {
    unsigned int ua = __float_as_uint(a);
    ua += 0x7fffu + ((ua >> 16) & 1u);
    return (unsigned short)(ua >> 16);
}

// stage one 4d x 4n register subtile into xdn (d-major) and xnd (n-major)
__device__ __forceinline__ void stage_group(int dbase, int n4, const float4* rr,
                                            unsigned short* xnd_s, unsigned short* xdn_s,
                                            f32x4& ssn) {
    float4 r0 = rr[0], r1 = rr[1], r2 = rr[2], r3 = rr[3];
    ssn.x = fmaf(r0.x, r0.x, ssn.x); ssn.x = fmaf(r1.x, r1.x, ssn.x);
    ssn.x = fmaf(r2.x, r2.x, ssn.x); ssn.x = fmaf(r3.x, r3.x, ssn.x);
    ssn.y = fmaf(r0.y, r0.y, ssn.y); ssn.y = fmaf(r1.y, r1.y, ssn.y);
    ssn.y = fmaf(r2.y, r2.y, ssn.y); ssn.y = fmaf(r3.y, r3.y, ssn.y);
    ssn.z = fmaf(r0.z, r0.z, ssn.z); ssn.z = fmaf(r1.z, r1.z, ssn.z);
    ssn.z = fmaf(r2.z, r2.z, ssn.z); ssn.z = fmaf(r3.z, r3.z, ssn.z);
    ssn.w = fmaf(r0.w, r0.w, ssn.w); ssn.w = fmaf(r1.w, r1.w, ssn.w);
    ssn.w = fmaf(r2.w, r2.w, ssn.w); ssn.w = fmaf(r3.w, r3.w, ssn.w);
#pragma unroll
    for (int j = 0; j < 4; j++) {  // xdn: row d, 4 consecutive n -> b64
        int d = dbase + j;
        uint2 u;
        u.x = bf16pair(rr[j].x, rr[j].y);
        u.y = bf16pair(rr[j].z, rr[j].w);
        *(uint2*)(xdn_s + d * 64 + ((((n4 >> 3) ^ (d & 7)) << 3) | (n4 & 7))) = u;
    }
    {  // xnd: row n, 4 consecutive d -> b64 (register transpose)
        float col[4][4] = {{r0.x, r1.x, r2.x, r3.x},
                           {r0.y, r1.y, r2.y, r3.y},
                           {r0.z, r1.z, r2.z, r3.z},
                           {r0.w, r1.w, r2.w, r3.w}};
#pragma unroll
        for (int j = 0; j < 4; j++) {
            int n = n4 + j;
            uint2 u;
            u.x = bf16pair(col[j][0], col[j][1]);
            u.y = bf16pair(col[j][2], col[j][3]);
            int blk = (dbase >> 3) ^ ((n >> 2) & 3);
            *(uint2*)(xnd_s + n * XSTR + (blk << 3) + (dbase & 7)) = u;
        }
    }
}

// ---------------- fused: L-GEMM -> softmax -> agg-GEMM ----------------
// R11: same grid (512 = 32 b x 16 chunks), same LDS tiles, same P, but the
// block's work is re-partitioned over 8 waves (512 threads) instead of 4:
//   - L-GEMM wave (kw = w&3, nh = w>>2): k-tile 16 x n-half 32 (lacc[2])
//   - agg-GEMM wave w: d-slice 32 x k 64 -> eacc[2][4] = 32 VGPRs (was 64)
//   - staging per-thread halves: pre[4]/cur[4]
// Per-wave peak regs ~110 -> __launch_bounds__(512,4) (cap 128) -> 2 blocks/CU
// = 16 waves/CU = 4 waves/SIMD: 2x the TLP of R10 on a latency-bound kernel
// (R9 PMC: MfmaUtil 3%, VALUBusy 10% -> idle waves, barrier/waitcnt-bound).
// LDS: 33792+32768+9216+2048+2048 = 79872 B; x2 blocks = 159744 <= 163840.
// S (a-sum) now needs a cross-nh combine: routed through dead red_s at the
// epilogue (+1 barrier, 64 threads). All per-element arithmetic identical;
// only partial-sum grouping of rn/denom changes (~ulp).
__global__ __launch_bounds__(512, 4) void k_fused(const float* __restrict__ X,
                                                  const float* __restrict__ C,
                                                  float* __restrict__ P,
                                                  float* __restrict__ Sp) {
    __shared__ unsigned short xnd_s[64 * XSTR];  // [n][d] bf16, 33792 B
    __shared__ unsigned short xdn_s[DD * 64];    // [d][n] bf16, 32768 B
    __shared__ unsigned short at_s[KK * 72];     // [k][n] bf16, 9216 B
    __shared__ float rn4[8 * 64];                // per-wave partial ||x_n||^2
    __shared__ float red_s[8 * 64];              // per-wave exp-sum [w][n]; reused for S-combine

    int t = threadIdx.x;
    int b = blockIdx.x >> 4, chunk = blockIdx.x & 15;
    int w = t >> 6, lane = t & 63, c = lane & 15, g = lane >> 4;
    int q2 = t >> 4;               // 4w + g in [0,32): staging row group
    int n4 = c * 4;
    int kw = w & 3, nh = w >> 2;   // L-GEMM split: k-tile kw, n-half nh

    const float* Xb = X + (size_t)b * DD * NN + chunk * 256;

    // ---- initial prefetch (pass 0): d-rows q2*4..q2*4+3 (covers d 0..127) ----
    float4 pre[4];
    {
        const float* xb = Xb + (size_t)(q2 * 4) * NN + n4;
#pragma unroll
        for (int j = 0; j < 4; j++) pre[j] = *(const float4*)(xb + (size_t)j * NN);
    }

    // ---- codeword fragments in registers + on-the-fly row norm ----
    short8 cnf[8];
    {
        int k = 16 * kw + c;
        const float* cp = C + k * DD;
        float4 v0[8], v1[8];
        float ss = 0.f;
#pragma unroll
        for (int ks = 0; ks < 8; ks++) {
            v0[ks] = *(const float4*)(cp + 32 * ks + 8 * g);
            v1[ks] = *(const float4*)(cp + 32 * ks + 8 * g + 4);
            ss = fmaf(v0[ks].x, v0[ks].x, ss); ss = fmaf(v0[ks].y, v0[ks].y, ss);
            ss = fmaf(v0[ks].z, v0[ks].z, ss); ss = fmaf(v0[ks].w, v0[ks].w, ss);
            ss = fmaf(v1[ks].x, v1[ks].x, ss); ss = fmaf(v1[ks].y, v1[ks].y, ss);
            ss = fmaf(v1[ks].z, v1[ks].z, ss); ss = fmaf(v1[ks].w, v1[ks].w, ss);
        }
        ss += __shfl_xor(ss, 16);
        ss += __shfl_xor(ss, 32);
        float r = 1.f / fmaxf(sqrtf(ss), EPSV);
#pragma unroll
        for (int ks = 0; ks < 8; ks++) {
            uint4 u;
            u.x = bf16pair(v0[ks].x * r, v0[ks].y * r);
            u.y = bf16pair(v0[ks].z * r, v0[ks].w * r);
            u.z = bf16pair(v1[ks].x * r, v1[ks].y * r);
            u.w = bf16pair(v1[ks].z * r, v1[ks].w * r);
            cnf[ks] = *(short8*)&u;
        }
    }

    f32x4 eacc[2][4];  // d = 32w + dt*16, k = kt*16
#pragma unroll
    for (int dt = 0; dt < 2; dt++)
#pragma unroll
        for (int kt = 0; kt < 4; kt++) eacc[dt][kt] = (f32x4){0.f, 0.f, 0.f, 0.f};
    float s_acc[4] = {0.f, 0.f, 0.f, 0.f};

    for (int p = 0; p < 4; p++) {
        // ---- issue d-half 1 of THIS pass before the barrier ----
        float4 cur[4];
        {
            const float* xb = Xb + (size_t)(q2 * 4 + 128) * NN + p * 64 + n4;
#pragma unroll
            for (int j = 0; j < 4; j++) cur[j] = *(const float4*)(xb + (size_t)j * NN);
        }
        __syncthreads();  // (A) prev-pass LDS reads done; staging may rewrite

        // ---- consume pre (d 0..127) while cur is in flight ----
        f32x4 ssn = (f32x4){0.f, 0.f, 0.f, 0.f};
        stage_group(q2 * 4, n4, pre, xnd_s, xdn_s, ssn);

        // ---- issue NEXT pass's d-half 0 now (pre regs dead): stays in
        //      flight across all barriers below ----
        if (p < 3) {
            const float* xb = Xb + (size_t)(q2 * 4) * NN + (p + 1) * 64 + n4;
#pragma unroll
            for (int j = 0; j < 4; j++) pre[j] = *(const float4*)(xb + (size_t)j * NN);
        }

        // ---- consume cur (d 128..255) ----
        stage_group(q2 * 4 + 128, n4, cur, xnd_s, xdn_s, ssn);

        // ---- row-norm partials: reduce over g via shfl, write rn4[w][n] ----
        ssn.x += __shfl_xor(ssn.x, 16); ssn.x += __shfl_xor(ssn.x, 32);
        ssn.y += __shfl_xor(ssn.y, 16); ssn.y += __shfl_xor(ssn.y, 32);
        ssn.z += __shfl_xor(ssn.z, 16); ssn.z += __shfl_xor(ssn.z, 32);
        ssn.w += __shfl_xor(ssn.w, 16); ssn.w += __shfl_xor(ssn.w, 32);
        if (g == 0) *(f32x4*)(rn4 + w * 64 + n4) = ssn;

        __syncthreads();  // (B) staging + rn4 visible

        // ---- L-GEMM: Lt[16kw..16kw+16 k][32nh..32nh+32 n] ----
        f32x4 lacc[2];
#pragma unroll
        for (int nt = 0; nt < 2; nt++) lacc[nt] = (f32x4){0.f, 0.f, 0.f, 0.f};
#pragma unroll
        for (int ks = 0; ks < 8; ks++) {
            short8 af = cnf[ks];
#pragma unroll
            for (int nt = 0; nt < 2; nt++) {
                int n = 32 * nh + nt * 16 + c;
                short8 bf = *(const short8*)(xnd_s + n * XSTR +
                                             (((4 * ks + g) ^ ((n >> 2) & 3)) << 3));
                lacc[nt] = __builtin_amdgcn_mfma_f32_16x16x32_bf16(af, bf, lacc[nt], 0, 0, 0);
            }
        }

        // ---- softmax (no max-subtract: cosine sims are in [-1,1]) ----
        float lv[2][4];
#pragma unroll
        for (int nt = 0; nt < 2; nt++) {
            int n = 32 * nh + nt * 16 + c;
            float ssq = rn4[n] + rn4[64 + n] + rn4[128 + n] + rn4[192 + n] +
                        rn4[256 + n] + rn4[320 + n] + rn4[384 + n] + rn4[448 + n];
            float rn = 1.f / fmaxf(sqrtf(ssq), EPSV);
            float s = 0.f;
#pragma unroll
            for (int r = 0; r < 4; r++) {
                lv[nt][r] = __expf(lacc[nt][r] * rn);
                s += lv[nt][r];
            }
            s += __shfl_xor(s, 16);
            s += __shfl_xor(s, 32);
            if (g == 0) red_s[w * 64 + n] = s;
        }
        __syncthreads();  // (D) red_s visible

#pragma unroll
        for (int nt = 0; nt < 2; nt++) {
            int n = 32 * nh + nt * 16 + c;
            float denom = red_s[(4 * nh + 0) * 64 + n] + red_s[(4 * nh + 1) * 64 + n] +
                          red_s[(4 * nh + 2) * 64 + n] + red_s[(4 * nh + 3) * 64 + n];
            float inv = 1.f / denom;
#pragma unroll
            for (int r = 0; r < 4; r++) {
                float a = lv[nt][r] * inv;
                s_acc[r] += a;
                int k = 16 * kw + 4 * g + r;
                at_s[k * 72 + ((((n >> 3) ^ (k & 7)) << 3) | (n & 7))] = bf16one(a);
            }
        }
        __syncthreads();  // (E) at_s visible

        // ---- agg-GEMM: Et[d = 32w..32w+32][k] += sum_n X[n][d] * A[n][k] ----
#pragma unroll
        for (int ks2 = 0; ks2 < 2; ks2++) {
            short8 bk[4];
#pragma unroll
            for (int kt = 0; kt < 4; kt++) {
                int k = kt * 16 + c;
                bk[kt] = *(const short8*)(at_s + k * 72 + (((4 * ks2 + g) ^ (k & 7)) << 3));
            }
#pragma unroll
            for (int dt = 0; dt < 2; dt++) {
                int d = 32 * w + dt * 16 + c;
                short8 af = *(const short8*)(xdn_s + d * 64 + (((4 * ks2 + g) ^ (d & 7)) << 3));
#pragma unroll
                for (int kt = 0; kt < 4; kt++)
                    eacc[dt][kt] =
                        __builtin_amdgcn_mfma_f32_16x16x32_bf16(af, bk[kt], eacc[dt][kt], 0, 0, 0);
            }
        }
    }

    // ---- epilogue: partials P[block][k][d] (d-contig float4) ----
    // eacc[dt][kt] r=0..3 -> d = 32w + dt*16 + 4g + r, k = kt*16 + c.
    float* Pb = P + (size_t)blockIdx.x * (DD * KK);
#pragma unroll
    for (int dt = 0; dt < 2; dt++)
#pragma unroll
        for (int kt = 0; kt < 4; kt++) {
            int k = kt * 16 + c;
            int d0 = 32 * w + dt * 16 + 4 * g;
            *(f32x4*)(Pb + (size_t)k * DD + d0) = eacc[dt][kt];
        }

    // ---- per-block S: lane-sum over c, then cross-nh combine via red_s ----
    // (epilogue red_s writes are WAR-safe: all pass-3 denom reads completed
    //  before barrier E of p=3, which precedes this point in every wave)
#pragma unroll
    for (int r = 0; r < 4; r++) {
        float v = s_acc[r];
        v += __shfl_xor(v, 1);
        v += __shfl_xor(v, 2);
        v += __shfl_xor(v, 4);
        v += __shfl_xor(v, 8);
        if (c == 0) red_s[w * 64 + 16 * kw + 4 * g + r] = v;  // [w][k]
    }
    __syncthreads();
    if (t < KK) {
        int k = t;
        int kw2 = k >> 4;
        Sp[blockIdx.x * 64 + k] = red_s[kw2 * 64 + k] + red_s[(kw2 + 4) * 64 + k];
    }
}

// ---------- finalize: sum 16 partials, subtract S*C ----------
// P is [block][k][d]; consecutive threads own consecutive d (float4 each):
// P reads 1KB-contiguous per wave, Sp wave-uniform (scalar), C + out coalesced.
__global__ __launch_bounds__(256) void k_fin(const float* __restrict__ P,
                                             const float* __restrict__ Sp,
                                             const float* __restrict__ C,
                                             float* __restrict__ out) {
    int idx = blockIdx.x * 256 + threadIdx.x;  // 131072 total = 32 b * 64 k * 64 d4
    int b = idx >> 12;
    int r = idx & 4095;
    int k = r >> 6;
    int d0 = (r & 63) * 4;
    const float* Pp = P + (size_t)b * 16 * (DD * KK) + k * DD + d0;
    const float* Sb = Sp + b * 16 * 64 + k;
    f32x4 e0 = (f32x4){0.f, 0.f, 0.f, 0.f};
    f32x4 e1 = (f32x4){0.f, 0.f, 0.f, 0.f};
    float s0 = 0.f, s1 = 0.f;
#pragma unroll
    for (int cc = 0; cc < 16; cc += 2) {
        f32x4 p0 = *(const f32x4*)(Pp + (size_t)cc * (DD * KK));
        f32x4 p1 = *(const f32x4*)(Pp + (size_t)(cc + 1) * (DD * KK));
        e0 += p0;
        e1 += p1;
        s0 += Sb[cc * 64];
        s1 += Sb[(cc + 1) * 64];
    }
    f32x4 cv = *(const f32x4*)(C + k * DD + d0);
    f32x4 e = e0 + e1;
    float s = s0 + s1;
    f32x4 o;
    o.x = e.x - s * cv.x;
    o.y = e.y - s * cv.y;
    o.z = e.z - s * cv.z;
    o.w = e.w - s * cv.w;
    *(f32x4*)(out + (size_t)(b * 64 + k) * DD + d0) = o;
}

// ---------- launch ----------
extern "C" void kernel_launch(void* const* d_in, const int* in_sizes, int n_in,
                              void* d_out, int out_size, void* d_ws, size_t ws_size,
                              hipStream_t stream) {
    const float* X = (const float*)d_in[0];
    const float* C = (const float*)d_in[1];
    float* out = (float*)d_out;
    unsigned char* ws = (unsigned char*)d_ws;

    // ws: Sp 512*64*4 = 131072 B | P 512*64*256*4 = 33554432 B ([block][k][d])
    float* Sp = (float*)ws;
    float* P = (float*)(ws + 131072);

    k_fused<<<512, 512, 0, stream>>>(X, C, P, Sp);
    k_fin<<<512, 256, 0, stream>>>(P, Sp, C, out);
}

// Round 5
// 211.749 us; speedup vs baseline: 1.0853x; 1.0853x over previous
//
#include <hip/hip_runtime.h>
#include <hip/hip_bf16.h>
#include <math.h>

// (B, D, H, W, K) = (32, 256, 64, 64, 64); N = H*W = 4096
#define BB 32
#define DD 256
#define NN 4096
#define KK 64
#define EPSV 1e-8f
#define XSTR 264   // xnd row stride (shorts): 528 B = 16B-aligned, bank-rotating

typedef __attribute__((ext_vector_type(8))) short short8;   // 8 bf16
typedef __attribute__((ext_vector_type(4))) float f32x4;

__device__ __forceinline__ unsigned int bf16pair(float a, float b) {
    __hip_bfloat162 h = __float22bfloat162_rn(make_float2(a, b));  // v_cvt_pk_bf16_f32 (RNE)
    return *(unsigned int*)&h;
}
__device__ __forceinline__ unsigned short bf16one(float a) {
    unsigned int ua = __float_as_uint(a);
    ua += 0x7fffu + ((ua >> 16) & 1u);
    return (unsigned short)(ua >> 16);
}

// stage one 4d x 4n register subtile into xdn (d-major) and xnd (n-major)
__device__ __forceinline__ void stage_group(int dbase, int n4, const float4* rr,
                                            unsigned short* xnd_s, unsigned short* xdn_s,
                                            f32x4& ssn) {
    float4 r0 = rr[0], r1 = rr[1], r2 = rr[2], r3 = rr[3];
    ssn.x = fmaf(r0.x, r0.x, ssn.x); ssn.x = fmaf(r1.x, r1.x, ssn.x);
    ssn.x = fmaf(r2.x, r2.x, ssn.x); ssn.x = fmaf(r3.x, r3.x, ssn.x);
    ssn.y = fmaf(r0.y, r0.y, ssn.y); ssn.y = fmaf(r1.y, r1.y, ssn.y);
    ssn.y = fmaf(r2.y, r2.y, ssn.y); ssn.y = fmaf(r3.y, r3.y, ssn.y);
    ssn.z = fmaf(r0.z, r0.z, ssn.z); ssn.z = fmaf(r1.z, r1.z, ssn.z);
    ssn.z = fmaf(r2.z, r2.z, ssn.z); ssn.z = fmaf(r3.z, r3.z, ssn.z);
    ssn.w = fmaf(r0.w, r0.w, ssn.w); ssn.w = fmaf(r1.w, r1.w, ssn.w);
    ssn.w = fmaf(r2.w, r2.w, ssn.w); ssn.w = fmaf(r3.w, r3.w, ssn.w);
#pragma unroll
    for (int j = 0; j < 4; j++) {  // xdn: row d, 4 consecutive n -> b64
        int d = dbase + j;
        uint2 u;
        u.x = bf16pair(rr[j].x, rr[j].y);
        u.y = bf16pair(rr[j].z, rr[j].w);
        *(uint2*)(xdn_s + d * 64 + ((((n4 >> 3) ^ (d & 7)) << 3) | (n4 & 7))) = u;
    }
    {  // xnd: row n, 4 consecutive d -> b64 (register transpose)
        float col[4][4] = {{r0.x, r1.x, r2.x, r3.x},
                           {r0.y, r1.y, r2.y, r3.y},
                           {r0.z, r1.z, r2.z, r3.z},
                           {r0.w, r1.w, r2.w, r3.w}};
#pragma unroll
        for (int j = 0; j < 4; j++) {
            int n = n4 + j;
            uint2 u;
            u.x = bf16pair(col[j][0], col[j][1]);
            u.y = bf16pair(col[j][2], col[j][3]);
            int blk = (dbase >> 3) ^ ((n >> 2) & 3);
            *(uint2*)(xnd_s + n * XSTR + (blk << 3) + (dbase & 7)) = u;
        }
    }
}

// ---------------- fused: L-GEMM -> softmax -> agg-GEMM ----------------
// R12 = R11 (8-wave/512-thread decomposition, verified-correct) with ONLY
// the launch-bounds register budget fixed:
//   __launch_bounds__(512,4) empirically capped arch VGPRs at 256/4 = 64
//   (R9: (256,2)->128; R11: (512,4)->64), forcing ~50 hot-loop regs to
//   scratch: WRITE_SIZE 66.7 MB vs 33.7 ideal, k_fused 91 us.
//   Live-set audit of R11: staging peak ~122 regs, L-GEMM ~104, agg ~112
//   -> fits a 128 budget with no spill. (512,2) sets cap 128, which still
//   permits 16 waves/CU = 4 waves/SIMD (LDS 79872 x2 = 159744 <= 163840).
// Expected: no spill, occupancy ~50%, 2x R10's TLP on a latency-bound
// kernel (R9/R11 PMC: MfmaUtil ~3%, VALUBusy ~12% -> idle-wave-dominated).
__global__ __launch_bounds__(512, 2) void k_fused(const float* __restrict__ X,
                                                  const float* __restrict__ C,
                                                  float* __restrict__ P,
                                                  float* __restrict__ Sp) {
    __shared__ unsigned short xnd_s[64 * XSTR];  // [n][d] bf16, 33792 B
    __shared__ unsigned short xdn_s[DD * 64];    // [d][n] bf16, 32768 B
    __shared__ unsigned short at_s[KK * 72];     // [k][n] bf16, 9216 B
    __shared__ float rn4[8 * 64];                // per-wave partial ||x_n||^2
    __shared__ float red_s[8 * 64];              // per-wave exp-sum [w][n]; reused for S-combine

    int t = threadIdx.x;
    int b = blockIdx.x >> 4, chunk = blockIdx.x & 15;
    int w = t >> 6, lane = t & 63, c = lane & 15, g = lane >> 4;
    int q2 = t >> 4;               // 4w + g in [0,32): staging row group
    int n4 = c * 4;
    int kw = w & 3, nh = w >> 2;   // L-GEMM split: k-tile kw, n-half nh

    const float* Xb = X + (size_t)b * DD * NN + chunk * 256;

    // ---- initial prefetch (pass 0): d-rows q2*4..q2*4+3 (covers d 0..127) ----
    float4 pre[4];
    {
        const float* xb = Xb + (size_t)(q2 * 4) * NN + n4;
#pragma unroll
        for (int j = 0; j < 4; j++) pre[j] = *(const float4*)(xb + (size_t)j * NN);
    }

    // ---- codeword fragments in registers + on-the-fly row norm ----
    short8 cnf[8];
    {
        int k = 16 * kw + c;
        const float* cp = C + k * DD;
        float4 v0[8], v1[8];
        float ss = 0.f;
#pragma unroll
        for (int ks = 0; ks < 8; ks++) {
            v0[ks] = *(const float4*)(cp + 32 * ks + 8 * g);
            v1[ks] = *(const float4*)(cp + 32 * ks + 8 * g + 4);
            ss = fmaf(v0[ks].x, v0[ks].x, ss); ss = fmaf(v0[ks].y, v0[ks].y, ss);
            ss = fmaf(v0[ks].z, v0[ks].z, ss); ss = fmaf(v0[ks].w, v0[ks].w, ss);
            ss = fmaf(v1[ks].x, v1[ks].x, ss); ss = fmaf(v1[ks].y, v1[ks].y, ss);
            ss = fmaf(v1[ks].z, v1[ks].z, ss); ss = fmaf(v1[ks].w, v1[ks].w, ss);
        }
        ss += __shfl_xor(ss, 16);
        ss += __shfl_xor(ss, 32);
        float r = 1.f / fmaxf(sqrtf(ss), EPSV);
#pragma unroll
        for (int ks = 0; ks < 8; ks++) {
            uint4 u;
            u.x = bf16pair(v0[ks].x * r, v0[ks].y * r);
            u.y = bf16pair(v0[ks].z * r, v0[ks].w * r);
            u.z = bf16pair(v1[ks].x * r, v1[ks].y * r);
            u.w = bf16pair(v1[ks].z * r, v1[ks].w * r);
            cnf[ks] = *(short8*)&u;
        }
    }

    f32x4 eacc[2][4];  // d = 32w + dt*16, k = kt*16
#pragma unroll
    for (int dt = 0; dt < 2; dt++)
#pragma unroll
        for (int kt = 0; kt < 4; kt++) eacc[dt][kt] = (f32x4){0.f, 0.f, 0.f, 0.f};
    float s_acc[4] = {0.f, 0.f, 0.f, 0.f};

    for (int p = 0; p < 4; p++) {
        // ---- issue d-half 1 of THIS pass before the barrier ----
        float4 cur[4];
        {
            const float* xb = Xb + (size_t)(q2 * 4 + 128) * NN + p * 64 + n4;
#pragma unroll
            for (int j = 0; j < 4; j++) cur[j] = *(const float4*)(xb + (size_t)j * NN);
        }
        __syncthreads();  // (A) prev-pass LDS reads done; staging may rewrite

        // ---- consume pre (d 0..127) while cur is in flight ----
        f32x4 ssn = (f32x4){0.f, 0.f, 0.f, 0.f};
        stage_group(q2 * 4, n4, pre, xnd_s, xdn_s, ssn);

        // ---- issue NEXT pass's d-half 0 now (pre regs dead): stays in
        //      flight across all barriers below ----
        if (p < 3) {
            const float* xb = Xb + (size_t)(q2 * 4) * NN + (p + 1) * 64 + n4;
#pragma unroll
            for (int j = 0; j < 4; j++) pre[j] = *(const float4*)(xb + (size_t)j * NN);
        }

        // ---- consume cur (d 128..255) ----
        stage_group(q2 * 4 + 128, n4, cur, xnd_s, xdn_s, ssn);

        // ---- row-norm partials: reduce over g via shfl, write rn4[w][n] ----
        ssn.x += __shfl_xor(ssn.x, 16); ssn.x += __shfl_xor(ssn.x, 32);
        ssn.y += __shfl_xor(ssn.y, 16); ssn.y += __shfl_xor(ssn.y, 32);
        ssn.z += __shfl_xor(ssn.z, 16); ssn.z += __shfl_xor(ssn.z, 32);
        ssn.w += __shfl_xor(ssn.w, 16); ssn.w += __shfl_xor(ssn.w, 32);
        if (g == 0) *(f32x4*)(rn4 + w * 64 + n4) = ssn;

        __syncthreads();  // (B) staging + rn4 visible

        // ---- L-GEMM: Lt[16kw..16kw+16 k][32nh..32nh+32 n] ----
        f32x4 lacc[2];
#pragma unroll
        for (int nt = 0; nt < 2; nt++) lacc[nt] = (f32x4){0.f, 0.f, 0.f, 0.f};
#pragma unroll
        for (int ks = 0; ks < 8; ks++) {
            short8 af = cnf[ks];
#pragma unroll
            for (int nt = 0; nt < 2; nt++) {
                int n = 32 * nh + nt * 16 + c;
                short8 bf = *(const short8*)(xnd_s + n * XSTR +
                                             (((4 * ks + g) ^ ((n >> 2) & 3)) << 3));
                lacc[nt] = __builtin_amdgcn_mfma_f32_16x16x32_bf16(af, bf, lacc[nt], 0, 0, 0);
            }
        }

        // ---- softmax (no max-subtract: cosine sims are in [-1,1]) ----
        float lv[2][4];
#pragma unroll
        for (int nt = 0; nt < 2; nt++) {
            int n = 32 * nh + nt * 16 + c;
            float ssq = rn4[n] + rn4[64 + n] + rn4[128 + n] + rn4[192 + n] +
                        rn4[256 + n] + rn4[320 + n] + rn4[384 + n] + rn4[448 + n];
            float rn = 1.f / fmaxf(sqrtf(ssq), EPSV);
            float s = 0.f;
#pragma unroll
            for (int r = 0; r < 4; r++) {
                lv[nt][r] = __expf(lacc[nt][r] * rn);
                s += lv[nt][r];
            }
            s += __shfl_xor(s, 16);
            s += __shfl_xor(s, 32);
            if (g == 0) red_s[w * 64 + n] = s;
        }
        __syncthreads();  // (D) red_s visible

#pragma unroll
        for (int nt = 0; nt < 2; nt++) {
            int n = 32 * nh + nt * 16 + c;
            float denom = red_s[(4 * nh + 0) * 64 + n] + red_s[(4 * nh + 1) * 64 + n] +
                          red_s[(4 * nh + 2) * 64 + n] + red_s[(4 * nh + 3) * 64 + n];
            float inv = 1.f / denom;
#pragma unroll
            for (int r = 0; r < 4; r++) {
                float a = lv[nt][r] * inv;
                s_acc[r] += a;
                int k = 16 * kw + 4 * g + r;
                at_s[k * 72 + ((((n >> 3) ^ (k & 7)) << 3) | (n & 7))] = bf16one(a);
            }
        }
        __syncthreads();  // (E) at_s visible

        // ---- agg-GEMM: Et[d = 32w..32w+32][k] += sum_n X[n][d] * A[n][k] ----
#pragma unroll
        for (int ks2 = 0; ks2 < 2; ks2++) {
            short8 bk[4];
#pragma unroll
            for (int kt = 0; kt < 4; kt++) {
                int k = kt * 16 + c;
                bk[kt] = *(const short8*)(at_s + k * 72 + (((4 * ks2 + g) ^ (k & 7)) << 3));
            }
#pragma unroll
            for (int dt = 0; dt < 2; dt++) {
                int d = 32 * w + dt * 16 + c;
                short8 af = *(const short8*)(xdn_s + d * 64 + (((4 * ks2 + g) ^ (d & 7)) << 3));
#pragma unroll
                for (int kt = 0; kt < 4; kt++)
                    eacc[dt][kt] =
                        __builtin_amdgcn_mfma_f32_16x16x32_bf16(af, bk[kt], eacc[dt][kt], 0, 0, 0);
            }
        }
    }

    // ---- epilogue: partials P[block][k][d] (d-contig float4) ----
    // eacc[dt][kt] r=0..3 -> d = 32w + dt*16 + 4g + r, k = kt*16 + c.
    float* Pb = P + (size_t)blockIdx.x * (DD * KK);
#pragma unroll
    for (int dt = 0; dt < 2; dt++)
#pragma unroll
        for (int kt = 0; kt < 4; kt++) {
            int k = kt * 16 + c;
            int d0 = 32 * w + dt * 16 + 4 * g;
            *(f32x4*)(Pb + (size_t)k * DD + d0) = eacc[dt][kt];
        }

    // ---- per-block S: lane-sum over c, then cross-nh combine via red_s ----
    // (epilogue red_s writes are WAR-safe: all pass-3 denom reads completed
    //  before barrier E of p=3, which precedes this point in every wave)
#pragma unroll
    for (int r = 0; r < 4; r++) {
        float v = s_acc[r];
        v += __shfl_xor(v, 1);
        v += __shfl_xor(v, 2);
        v += __shfl_xor(v, 4);
        v += __shfl_xor(v, 8);
        if (c == 0) red_s[w * 64 + 16 * kw + 4 * g + r] = v;  // [w][k]
    }
    __syncthreads();
    if (t < KK) {
        int k = t;
        int kw2 = k >> 4;
        Sp[blockIdx.x * 64 + k] = red_s[kw2 * 64 + k] + red_s[(kw2 + 4) * 64 + k];
    }
}

// ---------- finalize: sum 16 partials, subtract S*C ----------
// P is [block][k][d]; consecutive threads own consecutive d (float4 each):
// P reads 1KB-contiguous per wave, Sp wave-uniform (scalar), C + out coalesced.
__global__ __launch_bounds__(256) void k_fin(const float* __restrict__ P,
                                             const float* __restrict__ Sp,
                                             const float* __restrict__ C,
                                             float* __restrict__ out) {
    int idx = blockIdx.x * 256 + threadIdx.x;  // 131072 total = 32 b * 64 k * 64 d4
    int b = idx >> 12;
    int r = idx & 4095;
    int k = r >> 6;
    int d0 = (r & 63) * 4;
    const float* Pp = P + (size_t)b * 16 * (DD * KK) + k * DD + d0;
    const float* Sb = Sp + b * 16 * 64 + k;
    f32x4 e0 = (f32x4){0.f, 0.f, 0.f, 0.f};
    f32x4 e1 = (f32x4){0.f, 0.f, 0.f, 0.f};
    float s0 = 0.f, s1 = 0.f;
#pragma unroll
    for (int cc = 0; cc < 16; cc += 2) {
        f32x4 p0 = *(const f32x4*)(Pp + (size_t)cc * (DD * KK));
        f32x4 p1 = *(const f32x4*)(Pp + (size_t)(cc + 1) * (DD * KK));
        e0 += p0;
        e1 += p1;
        s0 += Sb[cc * 64];
        s1 += Sb[(cc + 1) * 64];
    }
    f32x4 cv = *(const f32x4*)(C + k * DD + d0);
    f32x4 e = e0 + e1;
    float s = s0 + s1;
    f32x4 o;
    o.x = e.x - s * cv.x;
    o.y = e.y - s * cv.y;
    o.z = e.z - s * cv.z;
    o.w = e.w - s * cv.w;
    *(f32x4*)(out + (size_t)(b * 64 + k) * DD + d0) = o;
}

// ---------- launch ----------
extern "C" void kernel_launch(void* const* d_in, const int* in_sizes, int n_in,
                              void* d_out, int out_size, void* d_ws, size_t ws_size,
                              hipStream_t stream) {
    const float* X = (const float*)d_in[0];
    const float* C = (const float*)d_in[1];
    float* out = (float*)d_out;
    unsigned char* ws = (unsigned char*)d_ws;

    // ws: Sp 512*64*4 = 131072 B | P 512*64*256*4 = 33554432 B ([block][k][d])
    float* Sp = (float*)ws;
    float* P = (float*)(ws + 131072);

    k_fused<<<512, 512, 0, stream>>>(X, C, P, Sp);
    k_fin<<<512, 256, 0, stream>>>(P, Sp, C, out);
}

// Round 6
// 211.472 us; speedup vs baseline: 1.0867x; 1.0013x over previous
//
#include <hip/hip_runtime.h>
#include <hip/hip_bf16.h>
#include <hip/hip_fp16.h>
#include <math.h>

// (B, D, H, W, K) = (32, 256, 64, 64, 64); N = H*W = 4096
#define BB 32
#define DD 256
#define NN 4096
#define KK 64
#define EPSV 1e-8f
#define XSTR 264   // xnd row stride (shorts): 528 B = 16B-aligned, bank-rotating

typedef __attribute__((ext_vector_type(8))) short short8;   // 8 bf16
typedef __attribute__((ext_vector_type(4))) float f32x4;

__device__ __forceinline__ unsigned int bf16pair(float a, float b) {
    __hip_bfloat162 h = __float22bfloat162_rn(make_float2(a, b));  // v_cvt_pk_bf16_f32 (RNE)
    return *(unsigned int*)&h;
}
__device__ __forceinline__ unsigned short bf16one(float a) {
    unsigned int ua = __float_as_uint(a);
    ua += 0x7fffu + ((ua >> 16) & 1u);
    return (unsigned short)(ua >> 16);
}
__device__ __forceinline__ unsigned int f16pair(float a, float b) {
    __half2 h = __float22half2_rn(make_float2(a, b));  // v_cvt_pk_f16_f32 (RNE)
    return *(unsigned int*)&h;
}

// stage one 4d x 4n register subtile into xdn (d-major) and xnd (n-major)
__device__ __forceinline__ void stage_group(int dbase, int n4, const float4* rr,
                                            unsigned short* xnd_s, unsigned short* xdn_s,
                                            f32x4& ssn) {
    float4 r0 = rr[0], r1 = rr[1], r2 = rr[2], r3 = rr[3];
    ssn.x = fmaf(r0.x, r0.x, ssn.x); ssn.x = fmaf(r1.x, r1.x, ssn.x);
    ssn.x = fmaf(r2.x, r2.x, ssn.x); ssn.x = fmaf(r3.x, r3.x, ssn.x);
    ssn.y = fmaf(r0.y, r0.y, ssn.y); ssn.y = fmaf(r1.y, r1.y, ssn.y);
    ssn.y = fmaf(r2.y, r2.y, ssn.y); ssn.y = fmaf(r3.y, r3.y, ssn.y);
    ssn.z = fmaf(r0.z, r0.z, ssn.z); ssn.z = fmaf(r1.z, r1.z, ssn.z);
    ssn.z = fmaf(r2.z, r2.z, ssn.z); ssn.z = fmaf(r3.z, r3.z, ssn.z);
    ssn.w = fmaf(r0.w, r0.w, ssn.w); ssn.w = fmaf(r1.w, r1.w, ssn.w);
    ssn.w = fmaf(r2.w, r2.w, ssn.w); ssn.w = fmaf(r3.w, r3.w, ssn.w);
#pragma unroll
    for (int j = 0; j < 4; j++) {  // xdn: row d, 4 consecutive n -> b64
        int d = dbase + j;
        uint2 u;
        u.x = bf16pair(rr[j].x, rr[j].y);
        u.y = bf16pair(rr[j].z, rr[j].w);
        *(uint2*)(xdn_s + d * 64 + ((((n4 >> 3) ^ (d & 7)) << 3) | (n4 & 7))) = u;
    }
    {  // xnd: row n, 4 consecutive d -> b64 (register transpose)
        float col[4][4] = {{r0.x, r1.x, r2.x, r3.x},
                           {r0.y, r1.y, r2.y, r3.y},
                           {r0.z, r1.z, r2.z, r3.z},
                           {r0.w, r1.w, r2.w, r3.w}};
#pragma unroll
        for (int j = 0; j < 4; j++) {
            int n = n4 + j;
            uint2 u;
            u.x = bf16pair(col[j][0], col[j][1]);
            u.y = bf16pair(col[j][2], col[j][3]);
            int blk = (dbase >> 3) ^ ((n >> 2) & 3);
            *(uint2*)(xnd_s + n * XSTR + (blk << 3) + (dbase & 7)) = u;
        }
    }
}

// ---------------- fused: L-GEMM -> softmax -> agg-GEMM ----------------
// R13 = R12 (verified 8-wave/512-thread, (512,2) no-spill) with ONE change:
// P partials stored in fp16 (33.5 -> 16.8 MB; round-trip saves 33.5 MB HBM).
// Rationale: R1->R5 delta analysis shows marginal exposure of kernel time in
// dur is only ~0.3 (fills overlap/contend) -> HBM BYTES are the lever, not
// kernel latency (R12: doubling waves/SIMD changed nothing).
// fp16 safety: A <= e/(64/e) ~ 0.115 (cosine sims in [-1,1]), |E_partial|
// <~ 3; fp16 RNE error <= 0.002/partial, 16 partials summed in f32.
__global__ __launch_bounds__(512, 2) void k_fused(const float* __restrict__ X,
                                                  const float* __restrict__ C,
                                                  __half* __restrict__ P,
                                                  float* __restrict__ Sp) {
    __shared__ unsigned short xnd_s[64 * XSTR];  // [n][d] bf16, 33792 B
    __shared__ unsigned short xdn_s[DD * 64];    // [d][n] bf16, 32768 B
    __shared__ unsigned short at_s[KK * 72];     // [k][n] bf16, 9216 B
    __shared__ float rn4[8 * 64];                // per-wave partial ||x_n||^2
    __shared__ float red_s[8 * 64];              // per-wave exp-sum [w][n]; reused for S-combine

    int t = threadIdx.x;
    int b = blockIdx.x >> 4, chunk = blockIdx.x & 15;
    int w = t >> 6, lane = t & 63, c = lane & 15, g = lane >> 4;
    int q2 = t >> 4;               // 4w + g in [0,32): staging row group
    int n4 = c * 4;
    int kw = w & 3, nh = w >> 2;   // L-GEMM split: k-tile kw, n-half nh

    const float* Xb = X + (size_t)b * DD * NN + chunk * 256;

    // ---- initial prefetch (pass 0): d-rows q2*4..q2*4+3 (covers d 0..127) ----
    float4 pre[4];
    {
        const float* xb = Xb + (size_t)(q2 * 4) * NN + n4;
#pragma unroll
        for (int j = 0; j < 4; j++) pre[j] = *(const float4*)(xb + (size_t)j * NN);
    }

    // ---- codeword fragments in registers + on-the-fly row norm ----
    short8 cnf[8];
    {
        int k = 16 * kw + c;
        const float* cp = C + k * DD;
        float4 v0[8], v1[8];
        float ss = 0.f;
#pragma unroll
        for (int ks = 0; ks < 8; ks++) {
            v0[ks] = *(const float4*)(cp + 32 * ks + 8 * g);
            v1[ks] = *(const float4*)(cp + 32 * ks + 8 * g + 4);
            ss = fmaf(v0[ks].x, v0[ks].x, ss); ss = fmaf(v0[ks].y, v0[ks].y, ss);
            ss = fmaf(v0[ks].z, v0[ks].z, ss); ss = fmaf(v0[ks].w, v0[ks].w, ss);
            ss = fmaf(v1[ks].x, v1[ks].x, ss); ss = fmaf(v1[ks].y, v1[ks].y, ss);
            ss = fmaf(v1[ks].z, v1[ks].z, ss); ss = fmaf(v1[ks].w, v1[ks].w, ss);
        }
        ss += __shfl_xor(ss, 16);
        ss += __shfl_xor(ss, 32);
        float r = 1.f / fmaxf(sqrtf(ss), EPSV);
#pragma unroll
        for (int ks = 0; ks < 8; ks++) {
            uint4 u;
            u.x = bf16pair(v0[ks].x * r, v0[ks].y * r);
            u.y = bf16pair(v0[ks].z * r, v0[ks].w * r);
            u.z = bf16pair(v1[ks].x * r, v1[ks].y * r);
            u.w = bf16pair(v1[ks].z * r, v1[ks].w * r);
            cnf[ks] = *(short8*)&u;
        }
    }

    f32x4 eacc[2][4];  // d = 32w + dt*16, k = kt*16
#pragma unroll
    for (int dt = 0; dt < 2; dt++)
#pragma unroll
        for (int kt = 0; kt < 4; kt++) eacc[dt][kt] = (f32x4){0.f, 0.f, 0.f, 0.f};
    float s_acc[4] = {0.f, 0.f, 0.f, 0.f};

    for (int p = 0; p < 4; p++) {
        // ---- issue d-half 1 of THIS pass before the barrier ----
        float4 cur[4];
        {
            const float* xb = Xb + (size_t)(q2 * 4 + 128) * NN + p * 64 + n4;
#pragma unroll
            for (int j = 0; j < 4; j++) cur[j] = *(const float4*)(xb + (size_t)j * NN);
        }
        __syncthreads();  // (A) prev-pass LDS reads done; staging may rewrite

        // ---- consume pre (d 0..127) while cur is in flight ----
        f32x4 ssn = (f32x4){0.f, 0.f, 0.f, 0.f};
        stage_group(q2 * 4, n4, pre, xnd_s, xdn_s, ssn);

        // ---- issue NEXT pass's d-half 0 now (pre regs dead): stays in
        //      flight across all barriers below ----
        if (p < 3) {
            const float* xb = Xb + (size_t)(q2 * 4) * NN + (p + 1) * 64 + n4;
#pragma unroll
            for (int j = 0; j < 4; j++) pre[j] = *(const float4*)(xb + (size_t)j * NN);
        }

        // ---- consume cur (d 128..255) ----
        stage_group(q2 * 4 + 128, n4, cur, xnd_s, xdn_s, ssn);

        // ---- row-norm partials: reduce over g via shfl, write rn4[w][n] ----
        ssn.x += __shfl_xor(ssn.x, 16); ssn.x += __shfl_xor(ssn.x, 32);
        ssn.y += __shfl_xor(ssn.y, 16); ssn.y += __shfl_xor(ssn.y, 32);
        ssn.z += __shfl_xor(ssn.z, 16); ssn.z += __shfl_xor(ssn.z, 32);
        ssn.w += __shfl_xor(ssn.w, 16); ssn.w += __shfl_xor(ssn.w, 32);
        if (g == 0) *(f32x4*)(rn4 + w * 64 + n4) = ssn;

        __syncthreads();  // (B) staging + rn4 visible

        // ---- L-GEMM: Lt[16kw..16kw+16 k][32nh..32nh+32 n] ----
        f32x4 lacc[2];
#pragma unroll
        for (int nt = 0; nt < 2; nt++) lacc[nt] = (f32x4){0.f, 0.f, 0.f, 0.f};
#pragma unroll
        for (int ks = 0; ks < 8; ks++) {
            short8 af = cnf[ks];
#pragma unroll
            for (int nt = 0; nt < 2; nt++) {
                int n = 32 * nh + nt * 16 + c;
                short8 bf = *(const short8*)(xnd_s + n * XSTR +
                                             (((4 * ks + g) ^ ((n >> 2) & 3)) << 3));
                lacc[nt] = __builtin_amdgcn_mfma_f32_16x16x32_bf16(af, bf, lacc[nt], 0, 0, 0);
            }
        }

        // ---- softmax (no max-subtract: cosine sims are in [-1,1]) ----
        float lv[2][4];
#pragma unroll
        for (int nt = 0; nt < 2; nt++) {
            int n = 32 * nh + nt * 16 + c;
            float ssq = rn4[n] + rn4[64 + n] + rn4[128 + n] + rn4[192 + n] +
                        rn4[256 + n] + rn4[320 + n] + rn4[384 + n] + rn4[448 + n];
            float rn = 1.f / fmaxf(sqrtf(ssq), EPSV);
            float s = 0.f;
#pragma unroll
            for (int r = 0; r < 4; r++) {
                lv[nt][r] = __expf(lacc[nt][r] * rn);
                s += lv[nt][r];
            }
            s += __shfl_xor(s, 16);
            s += __shfl_xor(s, 32);
            if (g == 0) red_s[w * 64 + n] = s;
        }
        __syncthreads();  // (D) red_s visible

#pragma unroll
        for (int nt = 0; nt < 2; nt++) {
            int n = 32 * nh + nt * 16 + c;
            float denom = red_s[(4 * nh + 0) * 64 + n] + red_s[(4 * nh + 1) * 64 + n] +
                          red_s[(4 * nh + 2) * 64 + n] + red_s[(4 * nh + 3) * 64 + n];
            float inv = 1.f / denom;
#pragma unroll
            for (int r = 0; r < 4; r++) {
                float a = lv[nt][r] * inv;
                s_acc[r] += a;
                int k = 16 * kw + 4 * g + r;
                at_s[k * 72 + ((((n >> 3) ^ (k & 7)) << 3) | (n & 7))] = bf16one(a);
            }
        }
        __syncthreads();  // (E) at_s visible

        // ---- agg-GEMM: Et[d = 32w..32w+32][k] += sum_n X[n][d] * A[n][k] ----
#pragma unroll
        for (int ks2 = 0; ks2 < 2; ks2++) {
            short8 bk[4];
#pragma unroll
            for (int kt = 0; kt < 4; kt++) {
                int k = kt * 16 + c;
                bk[kt] = *(const short8*)(at_s + k * 72 + (((4 * ks2 + g) ^ (k & 7)) << 3));
            }
#pragma unroll
            for (int dt = 0; dt < 2; dt++) {
                int d = 32 * w + dt * 16 + c;
                short8 af = *(const short8*)(xdn_s + d * 64 + (((4 * ks2 + g) ^ (d & 7)) << 3));
#pragma unroll
                for (int kt = 0; kt < 4; kt++)
                    eacc[dt][kt] =
                        __builtin_amdgcn_mfma_f32_16x16x32_bf16(af, bk[kt], eacc[dt][kt], 0, 0, 0);
            }
        }
    }

    // ---- epilogue: partials P[block][k][d] in fp16 (d-contig uint2) ----
    // eacc[dt][kt] r=0..3 -> d = 32w + dt*16 + 4g + r, k = kt*16 + c.
    __half* Pb = P + (size_t)blockIdx.x * (DD * KK);
#pragma unroll
    for (int dt = 0; dt < 2; dt++)
#pragma unroll
        for (int kt = 0; kt < 4; kt++) {
            int k = kt * 16 + c;
            int d0 = 32 * w + dt * 16 + 4 * g;
            f32x4 e = eacc[dt][kt];
            uint2 u;
            u.x = f16pair(e.x, e.y);
            u.y = f16pair(e.z, e.w);
            *(uint2*)(Pb + (size_t)k * DD + d0) = u;
        }

    // ---- per-block S: lane-sum over c, then cross-nh combine via red_s ----
#pragma unroll
    for (int r = 0; r < 4; r++) {
        float v = s_acc[r];
        v += __shfl_xor(v, 1);
        v += __shfl_xor(v, 2);
        v += __shfl_xor(v, 4);
        v += __shfl_xor(v, 8);
        if (c == 0) red_s[w * 64 + 16 * kw + 4 * g + r] = v;  // [w][k]
    }
    __syncthreads();
    if (t < KK) {
        int k = t;
        int kw2 = k >> 4;
        Sp[blockIdx.x * 64 + k] = red_s[kw2 * 64 + k] + red_s[(kw2 + 4) * 64 + k];
    }
}

// ---------- finalize: sum 16 fp16 partials (f32 accum), subtract S*C ----------
// P is [block][k][d] fp16; consecutive threads own consecutive d (uint2 each):
// per-partial wave read = 64 x 8 B contiguous; Sp wave-uniform; out coalesced.
__global__ __launch_bounds__(256) void k_fin(const __half* __restrict__ P,
                                             const float* __restrict__ Sp,
                                             const float* __restrict__ C,
                                             float* __restrict__ out) {
    int idx = blockIdx.x * 256 + threadIdx.x;  // 131072 total = 32 b * 64 k * 64 d4
    int b = idx >> 12;
    int r = idx & 4095;
    int k = r >> 6;
    int d0 = (r & 63) * 4;
    const __half* Pp = P + (size_t)b * 16 * (DD * KK) + k * DD + d0;
    const float* Sb = Sp + b * 16 * 64 + k;
    f32x4 e0 = (f32x4){0.f, 0.f, 0.f, 0.f};
    f32x4 e1 = (f32x4){0.f, 0.f, 0.f, 0.f};
    float s0 = 0.f, s1 = 0.f;
#pragma unroll
    for (int cc = 0; cc < 16; cc += 2) {
        uint2 v0 = *(const uint2*)(Pp + (size_t)cc * (DD * KK));
        uint2 v1 = *(const uint2*)(Pp + (size_t)(cc + 1) * (DD * KK));
        __half2 a0 = *(__half2*)&v0.x, a1 = *(__half2*)&v0.y;
        __half2 b0 = *(__half2*)&v1.x, b1 = *(__half2*)&v1.y;
        e0.x += __low2float(a0); e0.y += __high2float(a0);
        e0.z += __low2float(a1); e0.w += __high2float(a1);
        e1.x += __low2float(b0); e1.y += __high2float(b0);
        e1.z += __low2float(b1); e1.w += __high2float(b1);
        s0 += Sb[cc * 64];
        s1 += Sb[(cc + 1) * 64];
    }
    f32x4 cv = *(const f32x4*)(C + k * DD + d0);
    f32x4 e = e0 + e1;
    float s = s0 + s1;
    f32x4 o;
    o.x = e.x - s * cv.x;
    o.y = e.y - s * cv.y;
    o.z = e.z - s * cv.z;
    o.w = e.w - s * cv.w;
    *(f32x4*)(out + (size_t)(b * 64 + k) * DD + d0) = o;
}

// ---------- launch ----------
extern "C" void kernel_launch(void* const* d_in, const int* in_sizes, int n_in,
                              void* d_out, int out_size, void* d_ws, size_t ws_size,
                              hipStream_t stream) {
    const float* X = (const float*)d_in[0];
    const float* C = (const float*)d_in[1];
    float* out = (float*)d_out;
    unsigned char* ws = (unsigned char*)d_ws;

    // ws: Sp 512*64*4 = 131072 B | P 512*64*256*2 = 16777216 B (fp16 [block][k][d])
    float* Sp = (float*)ws;
    __half* P = (__half*)(ws + 131072);

    k_fused<<<512, 512, 0, stream>>>(X, C, P, Sp);
    k_fin<<<512, 256, 0, stream>>>(P, Sp, C, out);
}